// Round 8
// baseline (1711.581 us; speedup 1.0000x reference)
//
#include <hip/hip_runtime.h>
#include <math.h>

// ---------------- problem constants ----------------
#define B_    256
#define L_    128
#define IN_   6
#define D_    256
#define H_    8
#define NL_   6
#define E_    8
#define FF_   1024
#define NH_   5
#define NMOE_ 3
#define DK_   32
#define T_    (B_*L_)            // 32768 tokens
#define CAP_  66560              // T*2 + E*128 (buckets padded to 128)

typedef __bf16 bf16x8 __attribute__((ext_vector_type(8)));
typedef __bf16 bf16x4 __attribute__((ext_vector_type(4)));
typedef float  f32x4  __attribute__((ext_vector_type(4)));

// ---------------- workspace layout (byte offsets), total ~148 MB ----------------
static constexpr size_t OFF_H    = 0;            // f32  [T][256]   33,554,432
static constexpr size_t OFF_HB   = 33554432;     // bf16 [T][256]   16,777,216
static constexpr size_t OFF_QKV  = 50331648;     // bf16 [T][768]   50,331,648 (attn phase)
static constexpr size_t OFF_AO   = 100663296;    // bf16 [T][256]   16,777,216 (attn phase)
static constexpr size_t OFF_YOUT = 50331648;     // bf16 [CAP][256] 34,078,720 (moe phase, aliases QKV)
static constexpr size_t OFF_WQKV = 118489088;    // bf16 [6][768][256]
static constexpr size_t OFF_OWT  = 120848384;    // bf16 [6][256][256]
static constexpr size_t OFF_W1T  = 121634816;    // bf16 [3][8][1024][256]
static constexpr size_t OFF_W2T  = 134217728;    // bf16 [3][8][256][1024]
static constexpr size_t OFF_SMALL= 146800640;
static constexpr size_t SM_T2I   = OFF_SMALL + 0;        // int [2T]
static constexpr size_t SM_T2W   = OFF_SMALL + 262144;   // f32 [2T]
static constexpr size_t SM_SLOT  = OFF_SMALL + 524288;   // int [2T]
static constexpr size_t SM_PTOK  = OFF_SMALL + 786432;   // int [CAP]
static constexpr size_t SM_CNT   = OFF_SMALL + 1052672;  // int [8]
static constexpr size_t SM_POFF  = OFF_SMALL + 1052704;  // int [9]
static constexpr size_t SM_CUR   = OFF_SMALL + 1052740;  // int [8]

// gelu tanh-form; max abs err vs erf-form ~3e-4 << bf16 quantization here.
__device__ __forceinline__ float fast_gelu(float x) {
    float y  = 0.7978845608028654f * (x + 0.044715f * x * x * x);
    float ay = fabsf(y);
    float t  = __expf(-2.f * ay);
    float th = (1.f - t) / (1.f + t);
    th = copysignf(th, y);
    return 0.5f * x * (1.f + th);
}

// ---------------- transpose + cast weights to bf16 [n][k] ----------------
__global__ __launch_bounds__(256) void k_tcast(const float* __restrict__ src,
                                               __bf16* __restrict__ dst, int R, int C,
                                               size_t dbs, int rowoff) {
    __shared__ float tile[64][65];
    int b  = blockIdx.z;
    int r0 = blockIdx.y * 64, c0 = blockIdx.x * 64;
    const float* S = src + (size_t)b * R * C;
    __bf16* Dd = dst + (size_t)b * dbs;
    int tid = threadIdx.x;
#pragma unroll
    for (int i = 0; i < 4; ++i) {
        int f = tid + 256 * i;
        int r = f >> 4, c4 = (f & 15) * 4;
        float4 v = *(const float4*)(S + (size_t)(r0 + r) * C + c0 + c4);
        tile[r][c4] = v.x; tile[r][c4+1] = v.y; tile[r][c4+2] = v.z; tile[r][c4+3] = v.w;
    }
    __syncthreads();
#pragma unroll
    for (int i = 0; i < 2; ++i) {
        int chunk = tid + 256 * i;        // 512 chunks of 8 bf16
        int drow = chunk >> 3, seg = (chunk & 7) * 8;
        bf16x8 o;
#pragma unroll
        for (int j = 0; j < 8; ++j) o[j] = (__bf16)tile[seg + j][drow];
        *(bf16x8*)(Dd + (size_t)(rowoff + c0 + drow) * R + r0 + seg) = o;
    }
}

// ---------------- embed ----------------
__global__ void k_embed(const float* __restrict__ x, const float* __restrict__ ew,
                        const float* __restrict__ eb, float* __restrict__ h,
                        __bf16* __restrict__ hb) {
    int t = blockIdx.x;
    int d = threadIdx.x;
    const float* xr = x + (size_t)t * IN_;
    float acc = eb[d];
#pragma unroll
    for (int i = 0; i < IN_; ++i) acc = fmaf(xr[i], ew[i*D_ + d], acc);
    h[(size_t)t*D_ + d]  = acc;
    hb[(size_t)t*D_ + d] = (__bf16)acc;
}

// ---------------- bf16 MFMA 128x128 tile mainloop (256 thr, 4 waves) ----------------
#define LDT_ 40
__device__ __forceinline__ void mm_main(const __bf16* __restrict__ A, int lda,
                                        const __bf16* __restrict__ BT, int ldb,
                                        size_t m0, size_t n0, int K,
                                        f32x4 (&acc)[4][4],
                                        __bf16* As, __bf16* Bs) {
    const int tid  = threadIdx.x;
    const int lane = tid & 63, wid = tid >> 6;
    const int wm = (wid >> 1) * 64, wn = (wid & 1) * 64;
    const int lr = lane & 15, lq = lane >> 4;
    for (int k0 = 0; k0 < K; k0 += 32) {
#pragma unroll
        for (int i = 0; i < 2; ++i) {
            int f = tid + 256 * i;
            int row = f >> 2, q = (f & 3) * 8;
            *(bf16x8*)&As[row*LDT_ + q] = *(const bf16x8*)(A  + (m0 + row) * lda + k0 + q);
            *(bf16x8*)&Bs[row*LDT_ + q] = *(const bf16x8*)(BT + (n0 + row) * ldb + k0 + q);
        }
        __syncthreads();
        bf16x8 af[4], bfr[4];
#pragma unroll
        for (int mi = 0; mi < 4; ++mi) af[mi]  = *(bf16x8*)&As[(wm + mi*16 + lr)*LDT_ + lq*8];
#pragma unroll
        for (int ni = 0; ni < 4; ++ni) bfr[ni] = *(bf16x8*)&Bs[(wn + ni*16 + lr)*LDT_ + lq*8];
#pragma unroll
        for (int mi = 0; mi < 4; ++mi)
#pragma unroll
            for (int ni = 0; ni < 4; ++ni)
                acc[mi][ni] = __builtin_amdgcn_mfma_f32_16x16x32_bf16(af[mi], bfr[ni],
                                                                      acc[mi][ni], 0, 0, 0);
        __syncthreads();
    }
}

// C(bf16, ld=ldc) = A @ BT^T  (qkv: ldc=768)
__global__ __launch_bounds__(256) void k_mm_c(const __bf16* __restrict__ A,
                                              const __bf16* __restrict__ BT,
                                              __bf16* __restrict__ C, int ldc) {
    __shared__ __attribute__((aligned(16))) __bf16 As[128*LDT_], Bs[128*LDT_];
    f32x4 acc[4][4] = {};
    size_t m0 = (size_t)blockIdx.x * 128, n0 = (size_t)blockIdx.y * 128;
    mm_main(A, D_, BT, D_, m0, n0, D_, acc, As, Bs);
    const int lane = threadIdx.x & 63, wid = threadIdx.x >> 6;
    const int wm = (wid >> 1) * 64, wn = (wid & 1) * 64, lr = lane & 15, lq = lane >> 4;
#pragma unroll
    for (int mi = 0; mi < 4; ++mi)
#pragma unroll
        for (int r = 0; r < 4; ++r) {
            size_t gr = m0 + wm + mi*16 + lq*4 + r;
#pragma unroll
            for (int ni = 0; ni < 4; ++ni) {
                size_t gc = n0 + wn + ni*16 + lr;
                C[gr * ldc + gc] = (__bf16)acc[mi][ni][r];
            }
        }
}

// h += A @ BT^T (fp32 master), hb = bf16(h)
__global__ __launch_bounds__(256) void k_mm_oproj(const __bf16* __restrict__ A,
                                                  const __bf16* __restrict__ BT,
                                                  float* __restrict__ h,
                                                  __bf16* __restrict__ hb) {
    __shared__ __attribute__((aligned(16))) __bf16 As[128*LDT_], Bs[128*LDT_];
    f32x4 acc[4][4] = {};
    size_t m0 = (size_t)blockIdx.x * 128, n0 = (size_t)blockIdx.y * 128;
    mm_main(A, D_, BT, D_, m0, n0, D_, acc, As, Bs);
    const int lane = threadIdx.x & 63, wid = threadIdx.x >> 6;
    const int wm = (wid >> 1) * 64, wn = (wid & 1) * 64, lr = lane & 15, lq = lane >> 4;
#pragma unroll
    for (int mi = 0; mi < 4; ++mi)
#pragma unroll
        for (int r = 0; r < 4; ++r) {
            size_t gr = m0 + wm + mi*16 + lq*4 + r;
#pragma unroll
            for (int ni = 0; ni < 4; ++ni) {
                size_t gc = n0 + wn + ni*16 + lr;
                size_t idx = gr * D_ + gc;
                float nv = h[idx] + acc[mi][ni][r];
                h[idx]  = nv;
                hb[idx] = (__bf16)nv;
            }
        }
}

// ---------------- MFMA flash attention: one block per (b, head), 256 thr ----------------
__global__ __launch_bounds__(256) void k_attn_mfma(const __bf16* __restrict__ qkv,
                                                   const float* __restrict__ wfreq,
                                                   const float* __restrict__ wphase,
                                                   __bf16* __restrict__ ao) {
    __shared__ __attribute__((aligned(16))) char smem[44032];
    __bf16* Vt   = (__bf16*)smem;               // [32][136]     8704 B
    float*  wscp = (float*)(smem + 8704);       // [128]          512 B
    __bf16* Qs   = (__bf16*)(smem + 9216);      // [128][40]    10240 B
    __bf16* Ks   = (__bf16*)(smem + 19456);     // [128][40]    10240 B
    __bf16* Ps   = (__bf16*)(smem + 9216);      // [128][136], overlaps Qs/Ks after S

    int bh = blockIdx.x;
    int b = bh >> 3, hh = bh & 7;
    int tid = threadIdx.x;
    size_t tokbase = (size_t)b * L_ * 768 + (size_t)hh * 32;

#pragma unroll
    for (int j = 0; j < 2; ++j) {
        int chunk = tid + j*256;     // 512
        int row = chunk >> 2, seg = (chunk & 3) * 8;
        *(bf16x8*)&Qs[row*40 + seg] = *(const bf16x8*)(qkv + tokbase + (size_t)row*768 + seg);
        *(bf16x8*)&Ks[row*40 + seg] = *(const bf16x8*)(qkv + tokbase + 256 + (size_t)row*768 + seg);
    }
    {
        int kp = tid >> 1, dkb = (tid & 1) * 16;
        bf16x8 v0 = *(const bf16x8*)(qkv + tokbase + 512 + (size_t)kp*768 + dkb);
        bf16x8 v1 = *(const bf16x8*)(qkv + tokbase + 512 + (size_t)kp*768 + dkb + 8);
#pragma unroll
        for (int j = 0; j < 8; ++j) {
            Vt[(dkb + j)*136 + kp]     = v0[j];
            Vt[(dkb + 8 + j)*136 + kp] = v1[j];
        }
    }
    if (tid < 128) {
        float f = wfreq[hh], ph = wphase[hh];
        wscp[tid] = 0.1767766952966369f * cosf(6.283185307179586f * f * (float)tid + ph);
    }
    __syncthreads();

    const int lane = tid & 63, w = tid >> 6;
    const int lr = lane & 15, lq = lane >> 4;

    f32x4 sacc[2][8] = {};
#pragma unroll
    for (int mi = 0; mi < 2; ++mi) {
        bf16x8 af = *(const bf16x8*)&Qs[(w*32 + mi*16 + lr)*40 + lq*8];
#pragma unroll
        for (int ni = 0; ni < 8; ++ni) {
            bf16x8 bfr = *(const bf16x8*)&Ks[(ni*16 + lr)*40 + lq*8];
            sacc[mi][ni] = __builtin_amdgcn_mfma_f32_16x16x32_bf16(af, bfr, sacc[mi][ni], 0,0,0);
        }
    }
    float wr[8];
#pragma unroll
    for (int ni = 0; ni < 8; ++ni) wr[ni] = wscp[ni*16 + lr];
    __syncthreads();

#pragma unroll
    for (int mi = 0; mi < 2; ++mi)
#pragma unroll
        for (int r = 0; r < 4; ++r) {
            float vv[8]; float mx = -3.0e38f;
#pragma unroll
            for (int ni = 0; ni < 8; ++ni) { vv[ni] = sacc[mi][ni][r] * wr[ni]; mx = fmaxf(mx, vv[ni]); }
#pragma unroll
            for (int mk = 1; mk <= 8; mk <<= 1) mx = fmaxf(mx, __shfl_xor(mx, mk, 64));
            float sum = 0.f;
#pragma unroll
            for (int ni = 0; ni < 8; ++ni) { vv[ni] = __expf(vv[ni] - mx); sum += vv[ni]; }
#pragma unroll
            for (int mk = 1; mk <= 8; mk <<= 1) sum += __shfl_xor(sum, mk, 64);
            float inv = 1.f / sum;
            int row = w*32 + mi*16 + lq*4 + r;
#pragma unroll
            for (int ni = 0; ni < 8; ++ni)
                Ps[row*136 + ni*16 + lr] = (__bf16)(vv[ni] * inv);
        }
    __syncthreads();

    f32x4 oacc[2][2] = {};
#pragma unroll
    for (int kq = 0; kq < 4; ++kq) {
        bf16x8 paf[2], vbf[2];
#pragma unroll
        for (int mi = 0; mi < 2; ++mi)
            paf[mi] = *(const bf16x8*)&Ps[(w*32 + mi*16 + lr)*136 + kq*32 + lq*8];
#pragma unroll
        for (int ni = 0; ni < 2; ++ni)
            vbf[ni] = *(const bf16x8*)&Vt[(ni*16 + lr)*136 + kq*32 + lq*8];
#pragma unroll
        for (int mi = 0; mi < 2; ++mi)
#pragma unroll
            for (int ni = 0; ni < 2; ++ni)
                oacc[mi][ni] = __builtin_amdgcn_mfma_f32_16x16x32_bf16(paf[mi], vbf[ni],
                                                                       oacc[mi][ni], 0,0,0);
    }
    size_t obase = (size_t)b * L_ * D_ + (size_t)hh * 32;
#pragma unroll
    for (int mi = 0; mi < 2; ++mi)
#pragma unroll
        for (int ni = 0; ni < 2; ++ni)
#pragma unroll
            for (int r = 0; r < 4; ++r) {
                int row = w*32 + mi*16 + lq*4 + r;
                ao[obase + (size_t)row*D_ + ni*16 + lr] = (__bf16)oacc[mi][ni][r];
            }
}

// ---------------- MoE routing ----------------
__global__ void k_zero8(int* __restrict__ counts, int* __restrict__ cursors) {
    if (threadIdx.x < E_) { counts[threadIdx.x] = 0; cursors[threadIdx.x] = 0; }
}

__global__ __launch_bounds__(256) void k_router(const float* __restrict__ h,
                                                const float* __restrict__ rw,
                                                const float* __restrict__ rb,
                                                int* __restrict__ top2i,
                                                float* __restrict__ top2w) {
    int wv = threadIdx.x >> 6, lane = threadIdx.x & 63;
    int t = blockIdx.x * 4 + wv;
    float4 xv = *(const float4*)&h[(size_t)t * D_ + lane * 4];
    float lg[E_] = {};
    const float xs[4] = {xv.x, xv.y, xv.z, xv.w};
#pragma unroll
    for (int dd = 0; dd < 4; ++dd) {
        const float* rwr = rw + (size_t)(lane*4 + dd) * E_;
#pragma unroll
        for (int e = 0; e < E_; ++e) lg[e] = fmaf(xs[dd], rwr[e], lg[e]);
    }
#pragma unroll
    for (int e = 0; e < E_; ++e)
#pragma unroll
        for (int off = 32; off >= 1; off >>= 1) lg[e] += __shfl_down(lg[e], off, 64);
    if (lane == 0) {
        float val[E_];
#pragma unroll
        for (int e = 0; e < E_; ++e) val[e] = lg[e] + rb[e];
        int bi = 0; float best = val[0];
#pragma unroll
        for (int e = 1; e < E_; ++e) if (val[e] > best) { best = val[e]; bi = e; }
        int bi2 = -1; float best2 = -3.0e38f;
#pragma unroll
        for (int e = 0; e < E_; ++e) if (e != bi && val[e] > best2) { best2 = val[e]; bi2 = e; }
        float p2 = __expf(best2 - best);
        float inv = 1.f / (1.f + p2);
        top2i[2*t] = bi;  top2i[2*t+1] = bi2;
        top2w[2*t] = inv; top2w[2*t+1] = p2 * inv;
    }
}

__global__ __launch_bounds__(256) void k_hist(const int* __restrict__ t2i,
                                              int* __restrict__ cnt) {
    __shared__ int hc[E_];
    if (threadIdx.x < E_) hc[threadIdx.x] = 0;
    __syncthreads();
    for (int i = blockIdx.x * 256 + threadIdx.x; i < 2*T_; i += 64*256)
        atomicAdd(&hc[t2i[i]], 1);
    __syncthreads();
    if (threadIdx.x < E_) atomicAdd(&cnt[threadIdx.x], hc[threadIdx.x]);
}

__global__ void k_prefix(const int* __restrict__ counts, int* __restrict__ padoff) {
    if (threadIdx.x == 0 && blockIdx.x == 0) {
        int o = 0; padoff[0] = 0;
        for (int e = 0; e < E_; ++e) { o += (counts[e] + 127) & ~127; padoff[e+1] = o; }
    }
}

__global__ __launch_bounds__(256) void k_scatter(const int* __restrict__ top2i,
                                                 const int* __restrict__ padoff,
                                                 int* __restrict__ cursors,
                                                 int* __restrict__ pair_token,
                                                 int* __restrict__ slot_of) {
    int t = blockIdx.x * 256 + threadIdx.x;
    int lane = threadIdx.x & 63;
#pragma unroll
    for (int r = 0; r < 2; ++r) {
        int e = top2i[2*t + r];
#pragma unroll
        for (int e0 = 0; e0 < E_; ++e0) {
            unsigned long long m = __ballot(e == e0);
            if (m) {
                int leader = __ffsll((unsigned long long)m) - 1;
                int base = 0;
                if (lane == leader) base = atomicAdd(&cursors[e0], (int)__popcll(m));
                base = __shfl(base, leader, 64);
                if (e == e0) {
                    int rank = __popcll(m & ((1ull << lane) - 1ull));
                    int slot = padoff[e0] + base + rank;
                    pair_token[slot] = t;
                    slot_of[2*t + r] = slot;
                }
            }
        }
    }
}

// ---------------- fused expert FFN: yout[slot] = gelu(x@w1+b1)@w2 + b2 ----------------
// 64 rows/block, 8 waves (512 thr), R7 register layout (40 VGPR, 48% occ).
// Grid (8, 512): blockIdx.x = expert; flat wg id % 8 == blockIdx.x, and wg->XCD is
// round-robin by flat id, so all tiles of expert e land on XCD e -> the expert's
// 1 MB weight set is L2-resident (R7 counters: 1.04 GB/dispatch weight stream at
// 5.9 TB/s = L3 tier with all-expert working set 8 MB > 4 MB per-XCD L2).
__global__ __launch_bounds__(512) void k_moe_ffn(const __bf16* __restrict__ hb,
                                                 const __bf16* __restrict__ w1T,  // [E][FF][D]
                                                 const float*  __restrict__ b1,   // [E][FF]
                                                 const __bf16* __restrict__ w2T,  // [E][D][FF]
                                                 const float*  __restrict__ b2,   // [E][D]
                                                 const int* __restrict__ poff,
                                                 const int* __restrict__ ptok,
                                                 __bf16* __restrict__ yout) {
    __shared__ __attribute__((aligned(16))) __bf16 Xs[64*264];   // 33.8 KB
    __shared__ __attribute__((aligned(16))) __bf16 Ms[64*136];   // 17.4 KB
    __shared__ int sTok[64];
    const int tid = threadIdx.x;
    const int e = blockIdx.x;
    const int m0 = poff[e] + (int)blockIdx.y * 64;
    if (m0 >= poff[e + 1]) return;
    if (tid < 64) { int tk = ptok[m0 + tid]; sTok[tid] = tk < 0 ? 0 : tk; }
    __syncthreads();
#pragma unroll
    for (int j = 0; j < 4; ++j) {
        int chunk = tid + j * 512;        // 2048 chunks of bf16x8
        int r = chunk >> 5, c = (chunk & 31) * 8;
        *(bf16x8*)&Xs[r*264 + c] = *(const bf16x8*)(hb + (size_t)sTok[r]*D_ + c);
    }
    __syncthreads();
    const int lane = tid & 63, w = tid >> 6;      // w in 0..7
    const int lr = lane & 15, lq = lane >> 4;
    const __bf16* w1e = w1T + (size_t)e * FF_ * D_;
    const __bf16* w2e = w2T + (size_t)e * D_ * FF_;
    f32x4 oacc[4][2] = {};                        // 32 persistent regs
#pragma unroll 1
    for (int fc = 0; fc < 8; ++fc) {
        // GEMM1: wave owns ff cols [fc*128 + w*16, +16)
        f32x4 macc[4] = {};
        const int ff = fc*128 + w*16 + lr;
#pragma unroll
        for (int kq = 0; kq < 8; ++kq) {
            bf16x8 bw1 = *(const bf16x8*)(w1e + (size_t)ff*D_ + kq*32 + lq*8);
#pragma unroll
            for (int mi = 0; mi < 4; ++mi) {
                bf16x8 af = *(const bf16x8*)&Xs[(mi*16 + lr)*264 + kq*32 + lq*8];
                macc[mi] = __builtin_amdgcn_mfma_f32_16x16x32_bf16(af, bw1, macc[mi], 0,0,0);
            }
        }
        {
            float bv = b1[(size_t)e*FF_ + fc*128 + w*16 + lr];
#pragma unroll
            for (int mi = 0; mi < 4; ++mi)
#pragma unroll
                for (int r = 0; r < 4; ++r)
                    Ms[(mi*16 + lq*4 + r)*136 + w*16 + lr] = (__bf16)fast_gelu(macc[mi][r] + bv);
        }
        __syncthreads();
        // GEMM2: wave owns d cols [w*32, +32)
#pragma unroll
        for (int kq = 0; kq < 4; ++kq) {
            bf16x8 mf[4];
#pragma unroll
            for (int mi = 0; mi < 4; ++mi)
                mf[mi] = *(const bf16x8*)&Ms[(mi*16 + lr)*136 + kq*32 + lq*8];
#pragma unroll
            for (int ni = 0; ni < 2; ++ni) {
                int d = w*32 + ni*16 + lr;
                bf16x8 bw2 = *(const bf16x8*)(w2e + (size_t)d*FF_ + fc*128 + kq*32 + lq*8);
#pragma unroll
                for (int mi = 0; mi < 4; ++mi)
                    oacc[mi][ni] = __builtin_amdgcn_mfma_f32_16x16x32_bf16(mf[mi], bw2,
                                                                           oacc[mi][ni], 0,0,0);
            }
        }
        __syncthreads();   // protect Ms before next fc's writes
    }
#pragma unroll
    for (int ni = 0; ni < 2; ++ni) {
        int d = w*32 + ni*16 + lr;
        float bv = b2[(size_t)e*D_ + d];
#pragma unroll
        for (int mi = 0; mi < 4; ++mi)
#pragma unroll
            for (int r = 0; r < 4; ++r)
                yout[(size_t)(m0 + mi*16 + lq*4 + r)*D_ + d] = (__bf16)(oacc[mi][ni][r] + bv);
    }
}

// h[t] += wA*yout[slotA] + wB*yout[slotB]; hb = bf16(h)
__global__ __launch_bounds__(256) void k_combine(const __bf16* __restrict__ yout,
                                                 const int* __restrict__ slot_of,
                                                 const float* __restrict__ t2w,
                                                 float* __restrict__ h,
                                                 __bf16* __restrict__ hb) {
    size_t idx = (size_t)blockIdx.x * 256 + threadIdx.x;   // over T_*64
    int t = (int)(idx >> 6), c = (int)(idx & 63) * 4;
    int sA = slot_of[2*t], sB = slot_of[2*t + 1];
    float wA = t2w[2*t], wB = t2w[2*t + 1];
    bf16x4 a4 = *(const bf16x4*)&yout[(size_t)sA * D_ + c];
    bf16x4 b4 = *(const bf16x4*)&yout[(size_t)sB * D_ + c];
    size_t hi = (size_t)t * D_ + c;
    float4 hv = *(const float4*)&h[hi];
    float4 o;
    o.x = hv.x + wA*(float)a4[0] + wB*(float)b4[0];
    o.y = hv.y + wA*(float)a4[1] + wB*(float)b4[1];
    o.z = hv.z + wA*(float)a4[2] + wB*(float)b4[2];
    o.w = hv.w + wA*(float)a4[3] + wB*(float)b4[3];
    *(float4*)&h[hi] = o;
    bf16x4 ob; ob[0] = (__bf16)o.x; ob[1] = (__bf16)o.y; ob[2] = (__bf16)o.z; ob[3] = (__bf16)o.w;
    *(bf16x4*)&hb[hi] = ob;
}

// ---------------- final LN (pos L-1 only) + heads ----------------
__global__ __launch_bounds__(256) void k_head(const float* __restrict__ h,
                                              const float* __restrict__ g,
                                              const float* __restrict__ bb,
                                              const float* __restrict__ pw,
                                              const float* __restrict__ pb,
                                              const float* __restrict__ uw,
                                              const float* __restrict__ ub,
                                              float* __restrict__ out) {
    __shared__ float sred[4];
    __shared__ float smean, svar;
    __shared__ float z[D_];
    int b = blockIdx.x, t = threadIdx.x;
    int wv = t >> 6, ln = t & 63;
    float v = h[((size_t)b * L_ + (L_-1)) * D_ + t];
    float s = v;
#pragma unroll
    for (int off = 32; off >= 1; off >>= 1) s += __shfl_down(s, off, 64);
    if (ln == 0) sred[wv] = s;
    __syncthreads();
    if (t == 0) smean = (sred[0] + sred[1] + sred[2] + sred[3]) * (1.f/256.f);
    __syncthreads();
    float c = v - smean;
    float s2 = c * c;
#pragma unroll
    for (int off = 32; off >= 1; off >>= 1) s2 += __shfl_down(s2, off, 64);
    if (ln == 0) sred[wv] = s2;
    __syncthreads();
    if (t == 0) svar = (sred[0] + sred[1] + sred[2] + sred[3]) * (1.f/256.f);
    __syncthreads();
    z[t] = c * rsqrtf(svar + 1e-5f) * g[t] + bb[t];
    __syncthreads();
    for (int o = wv; o < NH_*2; o += 4) {
        const float* W = (o < NH_) ? pw : uw;
        int col = (o < NH_) ? o : o - NH_;
        float p = 0.f;
#pragma unroll
        for (int dd = 0; dd < 4; ++dd) {
            int d = ln*4 + dd;
            p = fmaf(z[d], W[(size_t)d * NH_ + col], p);
        }
#pragma unroll
        for (int off = 32; off >= 1; off >>= 1) p += __shfl_down(p, off, 64);
        if (ln == 0) {
            if (o < NH_) {
                out[(size_t)b * NH_ + o] = p + pb[o];
            } else {
                float xarg = p + ub[col];
                float sp = (xarg > 20.f) ? xarg : log1pf(expf(xarg));
                out[(size_t)B_ * NH_ + (size_t)b * NH_ + col] = sp;
            }
        }
    }
}

// ---------------- launcher ----------------
extern "C" void kernel_launch(void* const* d_in, const int* in_sizes, int n_in,
                              void* d_out, int out_size, void* d_ws, size_t ws_size,
                              hipStream_t stream) {
    const float* x        = (const float*)d_in[0];
    const float* emb_w    = (const float*)d_in[1];
    const float* emb_b    = (const float*)d_in[2];
    const float* qw       = (const float*)d_in[3];
    const float* kw       = (const float*)d_in[4];
    const float* vw       = (const float*)d_in[5];
    const float* ow       = (const float*)d_in[6];
    const float* wfreq    = (const float*)d_in[7];
    const float* wphase   = (const float*)d_in[8];
    const float* router_w = (const float*)d_in[9];
    const float* router_b = (const float*)d_in[10];
    const float* e_w1     = (const float*)d_in[11];
    const float* e_b1     = (const float*)d_in[12];
    const float* e_w2     = (const float*)d_in[13];
    const float* e_b2     = (const float*)d_in[14];
    const float* ln_g     = (const float*)d_in[15];
    const float* ln_b     = (const float*)d_in[16];
    const float* pred_w   = (const float*)d_in[17];
    const float* pred_b   = (const float*)d_in[18];
    const float* unc_w    = (const float*)d_in[19];
    const float* unc_b    = (const float*)d_in[20];
    float* out = (float*)d_out;

    char* W = (char*)d_ws;
    float*  h     = (float*)(W + OFF_H);
    __bf16* hb    = (__bf16*)(W + OFF_HB);
    __bf16* qkvb  = (__bf16*)(W + OFF_QKV);
    __bf16* aob   = (__bf16*)(W + OFF_AO);
    __bf16* yout  = (__bf16*)(W + OFF_YOUT);
    __bf16* wqkvT = (__bf16*)(W + OFF_WQKV);
    __bf16* owT   = (__bf16*)(W + OFF_OWT);
    __bf16* w1T   = (__bf16*)(W + OFF_W1T);
    __bf16* w2T   = (__bf16*)(W + OFF_W2T);
    int*    t2i   = (int*)(W + SM_T2I);
    float*  t2w   = (float*)(W + SM_T2W);
    int*    slot  = (int*)(W + SM_SLOT);
    int*    ptok  = (int*)(W + SM_PTOK);
    int*    cnt   = (int*)(W + SM_CNT);
    int*    poff  = (int*)(W + SM_POFF);
    int*    cur   = (int*)(W + SM_CUR);

    // weight prep
    {
        dim3 g44(4, 4, 6);
        k_tcast<<<g44, 256, 0, stream>>>(qw, wqkvT, 256, 256, (size_t)768*256, 0);
        k_tcast<<<g44, 256, 0, stream>>>(kw, wqkvT, 256, 256, (size_t)768*256, 256);
        k_tcast<<<g44, 256, 0, stream>>>(vw, wqkvT, 256, 256, (size_t)768*256, 512);
        k_tcast<<<g44, 256, 0, stream>>>(ow, owT,   256, 256, (size_t)256*256, 0);
        dim3 g1(16, 4, 24);
        k_tcast<<<g1, 256, 0, stream>>>(e_w1, w1T, 256, 1024, (size_t)1024*256, 0);
        dim3 g2(4, 16, 24);
        k_tcast<<<g2, 256, 0, stream>>>(e_w2, w2T, 1024, 256, (size_t)1024*256, 0);
    }

    k_embed<<<T_, D_, 0, stream>>>(x, emb_w, emb_b, h, hb);

    dim3 gqkv(T_/128, 6);
    dim3 gproj(T_/128, 2);
    dim3 gffn(E_, 512);          // x = expert (XCD-pinned); y covers worst-case rows
    for (int i = 0; i < NL_; ++i) {
        k_mm_c<<<gqkv, 256, 0, stream>>>(hb, wqkvT + (size_t)i*768*256, qkvb, 768);
        k_attn_mfma<<<B_*H_, 256, 0, stream>>>(qkvb, wfreq + i*H_, wphase + i*H_, aob);
        k_mm_oproj<<<gproj, 256, 0, stream>>>(aob, owT + (size_t)i*D_*D_, h, hb);

        if (i % 2 == 0 && i/2 < NMOE_) {
            int j = i / 2;
            k_zero8<<<1, 64, 0, stream>>>(cnt, cur);
            k_router<<<T_/4, 256, 0, stream>>>(h, router_w + (size_t)j*D_*E_,
                                               router_b + (size_t)j*E_, t2i, t2w);
            k_hist<<<64, 256, 0, stream>>>(t2i, cnt);
            k_prefix<<<1, 1, 0, stream>>>(cnt, poff);
            k_scatter<<<T_/256, 256, 0, stream>>>(t2i, poff, cur, ptok, slot);
            k_moe_ffn<<<gffn, 512, 0, stream>>>(hb,
                                                w1T + (size_t)j*E_*FF_*D_,
                                                e_b1 + (size_t)j*E_*FF_,
                                                w2T + (size_t)j*E_*D_*FF_,
                                                e_b2 + (size_t)j*E_*D_,
                                                poff, ptok, yout);
            k_combine<<<T_*64/256, 256, 0, stream>>>(yout, slot, t2w, h, hb);
        }
    }

    k_head<<<B_, 256, 0, stream>>>(h, ln_g, ln_b, pred_w, pred_b, unc_w, unc_b, out);
}

// Round 10
// 1566.334 us; speedup vs baseline: 1.0927x; 1.0927x over previous
//
#include <hip/hip_runtime.h>
#include <math.h>

// ---------------- problem constants ----------------
#define B_    256
#define L_    128
#define IN_   6
#define D_    256
#define H_    8
#define NL_   6
#define E_    8
#define FF_   1024
#define NH_   5
#define NMOE_ 3
#define DK_   32
#define T_    (B_*L_)            // 32768 tokens
#define CAP_  66560              // T*2 + E*128 (buckets padded to 128)

typedef __bf16 bf16x8 __attribute__((ext_vector_type(8)));
typedef __bf16 bf16x4 __attribute__((ext_vector_type(4)));
typedef float  f32x4  __attribute__((ext_vector_type(4)));

// ---------------- workspace layout (byte offsets), total ~148 MB ----------------
static constexpr size_t OFF_H    = 0;            // f32  [T][256]   33,554,432
static constexpr size_t OFF_HB   = 33554432;     // bf16 [T][256]   16,777,216
static constexpr size_t OFF_QKV  = 50331648;     // bf16 [T][768]   50,331,648 (attn phase)
static constexpr size_t OFF_AO   = 100663296;    // bf16 [T][256]   16,777,216 (attn phase)
static constexpr size_t OFF_YOUT = 50331648;     // bf16 [CAP][256] 34,078,720 (moe phase, aliases QKV)
static constexpr size_t OFF_WQKV = 118489088;    // bf16 [6][768][256]
static constexpr size_t OFF_OWT  = 120848384;    // bf16 [6][256][256]
static constexpr size_t OFF_W1T  = 121634816;    // bf16 [3][8][1024][256]
static constexpr size_t OFF_W2T  = 134217728;    // bf16 [3][8][256][1024]
static constexpr size_t OFF_SMALL= 146800640;
static constexpr size_t SM_T2I   = OFF_SMALL + 0;        // int [2T]
static constexpr size_t SM_T2W   = OFF_SMALL + 262144;   // f32 [2T]
static constexpr size_t SM_SLOT  = OFF_SMALL + 524288;   // int [2T]
static constexpr size_t SM_PTOK  = OFF_SMALL + 786432;   // int [CAP]
static constexpr size_t SM_CNT   = OFF_SMALL + 1052672;  // int [8]
static constexpr size_t SM_POFF  = OFF_SMALL + 1052704;  // int [9]
static constexpr size_t SM_CUR   = OFF_SMALL + 1052740;  // int [8]

// gelu tanh-form; max abs err vs erf-form ~3e-4 << bf16 floor here.
__device__ __forceinline__ float fast_gelu(float x) {
    float y  = 0.7978845608028654f * (x + 0.044715f * x * x * x);
    float ay = fabsf(y);
    float t  = __expf(-2.f * ay);
    float th = (1.f - t) / (1.f + t);
    th = copysignf(th, y);
    return 0.5f * x * (1.f + th);
}

// async global->LDS, 16B per lane; LDS dest is wave-uniform base + lane*16.
__device__ __forceinline__ void async_cp16(const __bf16* g, __bf16* lds_base) {
    __builtin_amdgcn_global_load_lds(
        (const __attribute__((address_space(1))) unsigned int*)g,
        (__attribute__((address_space(3))) unsigned int*)lds_base, 16, 0, 0);
}

// ---------------- transpose + cast weights to bf16 [n][k] ----------------
__global__ __launch_bounds__(256) void k_tcast(const float* __restrict__ src,
                                               __bf16* __restrict__ dst, int R, int C,
                                               size_t dbs, int rowoff) {
    __shared__ float tile[64][65];
    int b  = blockIdx.z;
    int r0 = blockIdx.y * 64, c0 = blockIdx.x * 64;
    const float* S = src + (size_t)b * R * C;
    __bf16* Dd = dst + (size_t)b * dbs;
    int tid = threadIdx.x;
#pragma unroll
    for (int i = 0; i < 4; ++i) {
        int f = tid + 256 * i;
        int r = f >> 4, c4 = (f & 15) * 4;
        float4 v = *(const float4*)(S + (size_t)(r0 + r) * C + c0 + c4);
        tile[r][c4] = v.x; tile[r][c4+1] = v.y; tile[r][c4+2] = v.z; tile[r][c4+3] = v.w;
    }
    __syncthreads();
#pragma unroll
    for (int i = 0; i < 2; ++i) {
        int chunk = tid + 256 * i;        // 512 chunks of 8 bf16
        int drow = chunk >> 3, seg = (chunk & 7) * 8;
        bf16x8 o;
#pragma unroll
        for (int j = 0; j < 8; ++j) o[j] = (__bf16)tile[seg + j][drow];
        *(bf16x8*)(Dd + (size_t)(rowoff + c0 + drow) * R + r0 + seg) = o;
    }
}

// ---------------- embed ----------------
__global__ void k_embed(const float* __restrict__ x, const float* __restrict__ ew,
                        const float* __restrict__ eb, float* __restrict__ h,
                        __bf16* __restrict__ hb) {
    int t = blockIdx.x;
    int d = threadIdx.x;
    const float* xr = x + (size_t)t * IN_;
    float acc = eb[d];
#pragma unroll
    for (int i = 0; i < IN_; ++i) acc = fmaf(xr[i], ew[i*D_ + d], acc);
    h[(size_t)t*D_ + d]  = acc;
    hb[(size_t)t*D_ + d] = (__bf16)acc;
}

// ---------------- bf16 MFMA 128x128 tile mainloop (256 thr, 4 waves) ----------------
// Staging via global_load_lds width=16 (m97 pattern): As/Bs UNPADDED [128][32]
// (async dest is wave-uniform base + lane*16 -> layout must be linear in chunk id).
__device__ __forceinline__ void mm_main(const __bf16* __restrict__ A, int lda,
                                        const __bf16* __restrict__ BT, int ldb,
                                        size_t m0, size_t n0, int K,
                                        f32x4 (&acc)[4][4],
                                        __bf16* As, __bf16* Bs) {
    const int tid  = threadIdx.x;
    const int lane = tid & 63, wid = tid >> 6;
    const int wm = (wid >> 1) * 64, wn = (wid & 1) * 64;
    const int lr = lane & 15, lq = lane >> 4;
    for (int k0 = 0; k0 < K; k0 += 32) {
#pragma unroll
        for (int j = 0; j < 2; ++j) {
            int cb = wid*64 + j*256;          // wave-uniform chunk base (0..511)
            int c  = cb + lane;               // this lane's chunk
            int row = c >> 2, seg = (c & 3) * 8;
            async_cp16(A  + (m0 + row) * lda + k0 + seg, As + (size_t)cb*8);
            async_cp16(BT + (n0 + row) * ldb + k0 + seg, Bs + (size_t)cb*8);
        }
        __syncthreads();
        bf16x8 af[4], bfr[4];
#pragma unroll
        for (int mi = 0; mi < 4; ++mi) af[mi]  = *(bf16x8*)&As[(wm + mi*16 + lr)*32 + lq*8];
#pragma unroll
        for (int ni = 0; ni < 4; ++ni) bfr[ni] = *(bf16x8*)&Bs[(wn + ni*16 + lr)*32 + lq*8];
#pragma unroll
        for (int mi = 0; mi < 4; ++mi)
#pragma unroll
            for (int ni = 0; ni < 4; ++ni)
                acc[mi][ni] = __builtin_amdgcn_mfma_f32_16x16x32_bf16(af[mi], bfr[ni],
                                                                      acc[mi][ni], 0, 0, 0);
        __syncthreads();
    }
}

// C(bf16, ld=ldc) = A @ BT^T  (qkv: ldc=768)
__global__ __launch_bounds__(256) void k_mm_c(const __bf16* __restrict__ A,
                                              const __bf16* __restrict__ BT,
                                              __bf16* __restrict__ C, int ldc) {
    __shared__ __attribute__((aligned(16))) __bf16 As[128*32], Bs[128*32];
    f32x4 acc[4][4] = {};
    size_t m0 = (size_t)blockIdx.x * 128, n0 = (size_t)blockIdx.y * 128;
    mm_main(A, D_, BT, D_, m0, n0, D_, acc, As, Bs);
    const int lane = threadIdx.x & 63, wid = threadIdx.x >> 6;
    const int wm = (wid >> 1) * 64, wn = (wid & 1) * 64, lr = lane & 15, lq = lane >> 4;
#pragma unroll
    for (int mi = 0; mi < 4; ++mi)
#pragma unroll
        for (int r = 0; r < 4; ++r) {
            size_t gr = m0 + wm + mi*16 + lq*4 + r;
#pragma unroll
            for (int ni = 0; ni < 4; ++ni) {
                size_t gc = n0 + wn + ni*16 + lr;
                C[gr * ldc + gc] = (__bf16)acc[mi][ni][r];
            }
        }
}

// h += A @ BT^T (fp32 master), hb = bf16(h)
__global__ __launch_bounds__(256) void k_mm_oproj(const __bf16* __restrict__ A,
                                                  const __bf16* __restrict__ BT,
                                                  float* __restrict__ h,
                                                  __bf16* __restrict__ hb) {
    __shared__ __attribute__((aligned(16))) __bf16 As[128*32], Bs[128*32];
    f32x4 acc[4][4] = {};
    size_t m0 = (size_t)blockIdx.x * 128, n0 = (size_t)blockIdx.y * 128;
    mm_main(A, D_, BT, D_, m0, n0, D_, acc, As, Bs);
    const int lane = threadIdx.x & 63, wid = threadIdx.x >> 6;
    const int wm = (wid >> 1) * 64, wn = (wid & 1) * 64, lr = lane & 15, lq = lane >> 4;
#pragma unroll
    for (int mi = 0; mi < 4; ++mi)
#pragma unroll
        for (int r = 0; r < 4; ++r) {
            size_t gr = m0 + wm + mi*16 + lq*4 + r;
#pragma unroll
            for (int ni = 0; ni < 4; ++ni) {
                size_t gc = n0 + wn + ni*16 + lr;
                size_t idx = gr * D_ + gc;
                float nv = h[idx] + acc[mi][ni][r];
                h[idx]  = nv;
                hb[idx] = (__bf16)nv;
            }
        }
}

// ---------------- MFMA flash attention: one block per (b, head), 256 thr ----------------
__global__ __launch_bounds__(256) void k_attn_mfma(const __bf16* __restrict__ qkv,
                                                   const float* __restrict__ wfreq,
                                                   const float* __restrict__ wphase,
                                                   __bf16* __restrict__ ao) {
    __shared__ __attribute__((aligned(16))) char smem[44032];
    __bf16* Vt   = (__bf16*)smem;               // [32][136]     8704 B
    float*  wscp = (float*)(smem + 8704);       // [128]          512 B
    __bf16* Qs   = (__bf16*)(smem + 9216);      // [128][40]    10240 B
    __bf16* Ks   = (__bf16*)(smem + 19456);     // [128][40]    10240 B
    __bf16* Ps   = (__bf16*)(smem + 9216);      // [128][136], overlaps Qs/Ks after S

    int bh = blockIdx.x;
    int b = bh >> 3, hh = bh & 7;
    int tid = threadIdx.x;
    size_t tokbase = (size_t)b * L_ * 768 + (size_t)hh * 32;

#pragma unroll
    for (int j = 0; j < 2; ++j) {
        int chunk = tid + j*256;     // 512
        int row = chunk >> 2, seg = (chunk & 3) * 8;
        *(bf16x8*)&Qs[row*40 + seg] = *(const bf16x8*)(qkv + tokbase + (size_t)row*768 + seg);
        *(bf16x8*)&Ks[row*40 + seg] = *(const bf16x8*)(qkv + tokbase + 256 + (size_t)row*768 + seg);
    }
    {
        int kp = tid >> 1, dkb = (tid & 1) * 16;
        bf16x8 v0 = *(const bf16x8*)(qkv + tokbase + 512 + (size_t)kp*768 + dkb);
        bf16x8 v1 = *(const bf16x8*)(qkv + tokbase + 512 + (size_t)kp*768 + dkb + 8);
#pragma unroll
        for (int j = 0; j < 8; ++j) {
            Vt[(dkb + j)*136 + kp]     = v0[j];
            Vt[(dkb + 8 + j)*136 + kp] = v1[j];
        }
    }
    if (tid < 128) {
        float f = wfreq[hh], ph = wphase[hh];
        wscp[tid] = 0.1767766952966369f * cosf(6.283185307179586f * f * (float)tid + ph);
    }
    __syncthreads();

    const int lane = tid & 63, w = tid >> 6;
    const int lr = lane & 15, lq = lane >> 4;

    f32x4 sacc[2][8] = {};
#pragma unroll
    for (int mi = 0; mi < 2; ++mi) {
        bf16x8 af = *(const bf16x8*)&Qs[(w*32 + mi*16 + lr)*40 + lq*8];
#pragma unroll
        for (int ni = 0; ni < 8; ++ni) {
            bf16x8 bfr = *(const bf16x8*)&Ks[(ni*16 + lr)*40 + lq*8];
            sacc[mi][ni] = __builtin_amdgcn_mfma_f32_16x16x32_bf16(af, bfr, sacc[mi][ni], 0,0,0);
        }
    }
    float wr[8];
#pragma unroll
    for (int ni = 0; ni < 8; ++ni) wr[ni] = wscp[ni*16 + lr];
    __syncthreads();

#pragma unroll
    for (int mi = 0; mi < 2; ++mi)
#pragma unroll
        for (int r = 0; r < 4; ++r) {
            float vv[8]; float mx = -3.0e38f;
#pragma unroll
            for (int ni = 0; ni < 8; ++ni) { vv[ni] = sacc[mi][ni][r] * wr[ni]; mx = fmaxf(mx, vv[ni]); }
#pragma unroll
            for (int mk = 1; mk <= 8; mk <<= 1) mx = fmaxf(mx, __shfl_xor(mx, mk, 64));
            float sum = 0.f;
#pragma unroll
            for (int ni = 0; ni < 8; ++ni) { vv[ni] = __expf(vv[ni] - mx); sum += vv[ni]; }
#pragma unroll
            for (int mk = 1; mk <= 8; mk <<= 1) sum += __shfl_xor(sum, mk, 64);
            float inv = 1.f / sum;
            int row = w*32 + mi*16 + lq*4 + r;
#pragma unroll
            for (int ni = 0; ni < 8; ++ni)
                Ps[row*136 + ni*16 + lr] = (__bf16)(vv[ni] * inv);
        }
    __syncthreads();

    f32x4 oacc[2][2] = {};
#pragma unroll
    for (int kq = 0; kq < 4; ++kq) {
        bf16x8 paf[2], vbf[2];
#pragma unroll
        for (int mi = 0; mi < 2; ++mi)
            paf[mi] = *(const bf16x8*)&Ps[(w*32 + mi*16 + lr)*136 + kq*32 + lq*8];
#pragma unroll
        for (int ni = 0; ni < 2; ++ni)
            vbf[ni] = *(const bf16x8*)&Vt[(ni*16 + lr)*136 + kq*32 + lq*8];
#pragma unroll
        for (int mi = 0; mi < 2; ++mi)
#pragma unroll
            for (int ni = 0; ni < 2; ++ni)
                oacc[mi][ni] = __builtin_amdgcn_mfma_f32_16x16x32_bf16(paf[mi], vbf[ni],
                                                                       oacc[mi][ni], 0,0,0);
    }
    size_t obase = (size_t)b * L_ * D_ + (size_t)hh * 32;
#pragma unroll
    for (int mi = 0; mi < 2; ++mi)
#pragma unroll
        for (int ni = 0; ni < 2; ++ni)
#pragma unroll
            for (int r = 0; r < 4; ++r) {
                int row = w*32 + mi*16 + lq*4 + r;
                ao[obase + (size_t)row*D_ + ni*16 + lr] = (__bf16)oacc[mi][ni][r];
            }
}

// ---------------- MoE routing ----------------
__global__ void k_zero8(int* __restrict__ counts, int* __restrict__ cursors) {
    if (threadIdx.x < E_) { counts[threadIdx.x] = 0; cursors[threadIdx.x] = 0; }
}

__global__ __launch_bounds__(256) void k_router(const float* __restrict__ h,
                                                const float* __restrict__ rw,
                                                const float* __restrict__ rb,
                                                int* __restrict__ top2i,
                                                float* __restrict__ top2w) {
    int wv = threadIdx.x >> 6, lane = threadIdx.x & 63;
    int t = blockIdx.x * 4 + wv;
    float4 xv = *(const float4*)&h[(size_t)t * D_ + lane * 4];
    float lg[E_] = {};
    const float xs[4] = {xv.x, xv.y, xv.z, xv.w};
#pragma unroll
    for (int dd = 0; dd < 4; ++dd) {
        const float* rwr = rw + (size_t)(lane*4 + dd) * E_;
#pragma unroll
        for (int e = 0; e < E_; ++e) lg[e] = fmaf(xs[dd], rwr[e], lg[e]);
    }
#pragma unroll
    for (int e = 0; e < E_; ++e)
#pragma unroll
        for (int off = 32; off >= 1; off >>= 1) lg[e] += __shfl_down(lg[e], off, 64);
    if (lane == 0) {
        float val[E_];
#pragma unroll
        for (int e = 0; e < E_; ++e) val[e] = lg[e] + rb[e];
        int bi = 0; float best = val[0];
#pragma unroll
        for (int e = 1; e < E_; ++e) if (val[e] > best) { best = val[e]; bi = e; }
        int bi2 = -1; float best2 = -3.0e38f;
#pragma unroll
        for (int e = 0; e < E_; ++e) if (e != bi && val[e] > best2) { best2 = val[e]; bi2 = e; }
        float p2 = __expf(best2 - best);
        float inv = 1.f / (1.f + p2);
        top2i[2*t] = bi;  top2i[2*t+1] = bi2;
        top2w[2*t] = inv; top2w[2*t+1] = p2 * inv;
    }
}

__global__ __launch_bounds__(256) void k_hist(const int* __restrict__ t2i,
                                              int* __restrict__ cnt) {
    __shared__ int hc[E_];
    if (threadIdx.x < E_) hc[threadIdx.x] = 0;
    __syncthreads();
    for (int i = blockIdx.x * 256 + threadIdx.x; i < 2*T_; i += 64*256)
        atomicAdd(&hc[t2i[i]], 1);
    __syncthreads();
    if (threadIdx.x < E_) atomicAdd(&cnt[threadIdx.x], hc[threadIdx.x]);
}

__global__ void k_prefix(const int* __restrict__ counts, int* __restrict__ padoff) {
    if (threadIdx.x == 0 && blockIdx.x == 0) {
        int o = 0; padoff[0] = 0;
        for (int e = 0; e < E_; ++e) { o += (counts[e] + 127) & ~127; padoff[e+1] = o; }
    }
}

__global__ __launch_bounds__(256) void k_scatter(const int* __restrict__ top2i,
                                                 const int* __restrict__ padoff,
                                                 int* __restrict__ cursors,
                                                 int* __restrict__ pair_token,
                                                 int* __restrict__ slot_of) {
    int t = blockIdx.x * 256 + threadIdx.x;
    int lane = threadIdx.x & 63;
#pragma unroll
    for (int r = 0; r < 2; ++r) {
        int e = top2i[2*t + r];
#pragma unroll
        for (int e0 = 0; e0 < E_; ++e0) {
            unsigned long long m = __ballot(e == e0);
            if (m) {
                int leader = __ffsll((unsigned long long)m) - 1;
                int base = 0;
                if (lane == leader) base = atomicAdd(&cursors[e0], (int)__popcll(m));
                base = __shfl(base, leader, 64);
                if (e == e0) {
                    int rank = __popcll(m & ((1ull << lane) - 1ull));
                    int slot = padoff[e0] + base + rank;
                    pair_token[slot] = t;
                    slot_of[2*t + r] = slot;
                }
            }
        }
    }
}

// ---------------- fused expert FFN (R7 bf16, verbatim): 64 rows/block, 8 waves -----
__global__ __launch_bounds__(512) void k_moe_ffn(const __bf16* __restrict__ hb,
                                                 const __bf16* __restrict__ w1T,  // [E][FF][D]
                                                 const float*  __restrict__ b1,   // [E][FF]
                                                 const __bf16* __restrict__ w2T,  // [E][D][FF]
                                                 const float*  __restrict__ b2,   // [E][D]
                                                 const int* __restrict__ poff,
                                                 const int* __restrict__ ptok,
                                                 __bf16* __restrict__ yout) {
    __shared__ __attribute__((aligned(16))) __bf16 Xs[64*264];   // 33.8 KB
    __shared__ __attribute__((aligned(16))) __bf16 Ms[64*136];   // 17.4 KB
    __shared__ int sOff[E_ + 1];
    __shared__ int sTok[64];
    const int tid = threadIdx.x;
    if (tid <= E_) sOff[tid] = poff[tid];
    __syncthreads();
    const int m0 = (int)blockIdx.x * 64;
    if (m0 >= sOff[E_]) return;
    int e = 0;
    while (m0 >= sOff[e + 1]) ++e;
    if (tid < 64) { int tk = ptok[m0 + tid]; sTok[tid] = tk < 0 ? 0 : tk; }
    __syncthreads();
#pragma unroll
    for (int j = 0; j < 4; ++j) {
        int chunk = tid + j * 512;        // 2048 chunks of bf16x8
        int r = chunk >> 5, c = (chunk & 31) * 8;
        *(bf16x8*)&Xs[r*264 + c] = *(const bf16x8*)(hb + (size_t)sTok[r]*D_ + c);
    }
    __syncthreads();
    const int lane = tid & 63, w = tid >> 6;      // w in 0..7
    const int lr = lane & 15, lq = lane >> 4;
    const __bf16* w1e = w1T + (size_t)e * FF_ * D_;
    const __bf16* w2e = w2T + (size_t)e * D_ * FF_;
    f32x4 oacc[4][2] = {};                        // 32 persistent regs
#pragma unroll 1
    for (int fc = 0; fc < 8; ++fc) {
        // GEMM1: wave owns ff cols [fc*128 + w*16, +16)
        f32x4 macc[4] = {};
        const int ff = fc*128 + w*16 + lr;
#pragma unroll
        for (int kq = 0; kq < 8; ++kq) {
            bf16x8 bw1 = *(const bf16x8*)(w1e + (size_t)ff*D_ + kq*32 + lq*8);
#pragma unroll
            for (int mi = 0; mi < 4; ++mi) {
                bf16x8 af = *(const bf16x8*)&Xs[(mi*16 + lr)*264 + kq*32 + lq*8];
                macc[mi] = __builtin_amdgcn_mfma_f32_16x16x32_bf16(af, bw1, macc[mi], 0,0,0);
            }
        }
        {
            float bv = b1[(size_t)e*FF_ + fc*128 + w*16 + lr];
#pragma unroll
            for (int mi = 0; mi < 4; ++mi)
#pragma unroll
                for (int r = 0; r < 4; ++r)
                    Ms[(mi*16 + lq*4 + r)*136 + w*16 + lr] = (__bf16)fast_gelu(macc[mi][r] + bv);
        }
        __syncthreads();
        // GEMM2: wave owns d cols [w*32, +32)
#pragma unroll
        for (int kq = 0; kq < 4; ++kq) {
            bf16x8 mf[4];
#pragma unroll
            for (int mi = 0; mi < 4; ++mi)
                mf[mi] = *(const bf16x8*)&Ms[(mi*16 + lr)*136 + kq*32 + lq*8];
#pragma unroll
            for (int ni = 0; ni < 2; ++ni) {
                int d = w*32 + ni*16 + lr;
                bf16x8 bw2 = *(const bf16x8*)(w2e + (size_t)d*FF_ + fc*128 + kq*32 + lq*8);
#pragma unroll
                for (int mi = 0; mi < 4; ++mi)
                    oacc[mi][ni] = __builtin_amdgcn_mfma_f32_16x16x32_bf16(mf[mi], bw2,
                                                                           oacc[mi][ni], 0,0,0);
            }
        }
        __syncthreads();   // protect Ms before next fc's writes
    }
#pragma unroll
    for (int ni = 0; ni < 2; ++ni) {
        int d = w*32 + ni*16 + lr;
        float bv = b2[(size_t)e*D_ + d];
#pragma unroll
        for (int mi = 0; mi < 4; ++mi)
#pragma unroll
            for (int r = 0; r < 4; ++r)
                yout[(size_t)(m0 + mi*16 + lq*4 + r)*D_ + d] = (__bf16)(oacc[mi][ni][r] + bv);
    }
}

// h[t] += wA*yout[slotA] + wB*yout[slotB]; hb = bf16(h)
__global__ __launch_bounds__(256) void k_combine(const __bf16* __restrict__ yout,
                                                 const int* __restrict__ slot_of,
                                                 const float* __restrict__ t2w,
                                                 float* __restrict__ h,
                                                 __bf16* __restrict__ hb) {
    size_t idx = (size_t)blockIdx.x * 256 + threadIdx.x;   // over T_*64
    int t = (int)(idx >> 6), c = (int)(idx & 63) * 4;
    int sA = slot_of[2*t], sB = slot_of[2*t + 1];
    float wA = t2w[2*t], wB = t2w[2*t + 1];
    bf16x4 a4 = *(const bf16x4*)&yout[(size_t)sA * D_ + c];
    bf16x4 b4 = *(const bf16x4*)&yout[(size_t)sB * D_ + c];
    size_t hi = (size_t)t * D_ + c;
    float4 hv = *(const float4*)&h[hi];
    float4 o;
    o.x = hv.x + wA*(float)a4[0] + wB*(float)b4[0];
    o.y = hv.y + wA*(float)a4[1] + wB*(float)b4[1];
    o.z = hv.z + wA*(float)a4[2] + wB*(float)b4[2];
    o.w = hv.w + wA*(float)a4[3] + wB*(float)b4[3];
    *(float4*)&h[hi] = o;
    bf16x4 ob; ob[0] = (__bf16)o.x; ob[1] = (__bf16)o.y; ob[2] = (__bf16)o.z; ob[3] = (__bf16)o.w;
    *(bf16x4*)&hb[hi] = ob;
}

// ---------------- final LN (pos L-1 only) + heads ----------------
__global__ __launch_bounds__(256) void k_head(const float* __restrict__ h,
                                              const float* __restrict__ g,
                                              const float* __restrict__ bb,
                                              const float* __restrict__ pw,
                                              const float* __restrict__ pb,
                                              const float* __restrict__ uw,
                                              const float* __restrict__ ub,
                                              float* __restrict__ out) {
    __shared__ float sred[4];
    __shared__ float smean, svar;
    __shared__ float z[D_];
    int b = blockIdx.x, t = threadIdx.x;
    int wv = t >> 6, ln = t & 63;
    float v = h[((size_t)b * L_ + (L_-1)) * D_ + t];
    float s = v;
#pragma unroll
    for (int off = 32; off >= 1; off >>= 1) s += __shfl_down(s, off, 64);
    if (ln == 0) sred[wv] = s;
    __syncthreads();
    if (t == 0) smean = (sred[0] + sred[1] + sred[2] + sred[3]) * (1.f/256.f);
    __syncthreads();
    float c = v - smean;
    float s2 = c * c;
#pragma unroll
    for (int off = 32; off >= 1; off >>= 1) s2 += __shfl_down(s2, off, 64);
    if (ln == 0) sred[wv] = s2;
    __syncthreads();
    if (t == 0) svar = (sred[0] + sred[1] + sred[2] + sred[3]) * (1.f/256.f);
    __syncthreads();
    z[t] = c * rsqrtf(svar + 1e-5f) * g[t] + bb[t];
    __syncthreads();
    for (int o = wv; o < NH_*2; o += 4) {
        const float* W = (o < NH_) ? pw : uw;
        int col = (o < NH_) ? o : o - NH_;
        float p = 0.f;
#pragma unroll
        for (int dd = 0; dd < 4; ++dd) {
            int d = ln*4 + dd;
            p = fmaf(z[d], W[(size_t)d * NH_ + col], p);
        }
#pragma unroll
        for (int off = 32; off >= 1; off >>= 1) p += __shfl_down(p, off, 64);
        if (ln == 0) {
            if (o < NH_) {
                out[(size_t)b * NH_ + o] = p + pb[o];
            } else {
                float xarg = p + ub[col];
                float sp = (xarg > 20.f) ? xarg : log1pf(expf(xarg));
                out[(size_t)B_ * NH_ + (size_t)b * NH_ + col] = sp;
            }
        }
    }
}

// ---------------- launcher ----------------
extern "C" void kernel_launch(void* const* d_in, const int* in_sizes, int n_in,
                              void* d_out, int out_size, void* d_ws, size_t ws_size,
                              hipStream_t stream) {
    const float* x        = (const float*)d_in[0];
    const float* emb_w    = (const float*)d_in[1];
    const float* emb_b    = (const float*)d_in[2];
    const float* qw       = (const float*)d_in[3];
    const float* kw       = (const float*)d_in[4];
    const float* vw       = (const float*)d_in[5];
    const float* ow       = (const float*)d_in[6];
    const float* wfreq    = (const float*)d_in[7];
    const float* wphase   = (const float*)d_in[8];
    const float* router_w = (const float*)d_in[9];
    const float* router_b = (const float*)d_in[10];
    const float* e_w1     = (const float*)d_in[11];
    const float* e_b1     = (const float*)d_in[12];
    const float* e_w2     = (const float*)d_in[13];
    const float* e_b2     = (const float*)d_in[14];
    const float* ln_g     = (const float*)d_in[15];
    const float* ln_b     = (const float*)d_in[16];
    const float* pred_w   = (const float*)d_in[17];
    const float* pred_b   = (const float*)d_in[18];
    const float* unc_w    = (const float*)d_in[19];
    const float* unc_b    = (const float*)d_in[20];
    float* out = (float*)d_out;

    char* W = (char*)d_ws;
    float*  h     = (float*)(W + OFF_H);
    __bf16* hb    = (__bf16*)(W + OFF_HB);
    __bf16* qkvb  = (__bf16*)(W + OFF_QKV);
    __bf16* aob   = (__bf16*)(W + OFF_AO);
    __bf16* yout  = (__bf16*)(W + OFF_YOUT);
    __bf16* wqkvT = (__bf16*)(W + OFF_WQKV);
    __bf16* owT   = (__bf16*)(W + OFF_OWT);
    __bf16* w1T   = (__bf16*)(W + OFF_W1T);
    __bf16* w2T   = (__bf16*)(W + OFF_W2T);
    int*    t2i   = (int*)(W + SM_T2I);
    float*  t2w   = (float*)(W + SM_T2W);
    int*    slot  = (int*)(W + SM_SLOT);
    int*    ptok  = (int*)(W + SM_PTOK);
    int*    cnt   = (int*)(W + SM_CNT);
    int*    poff  = (int*)(W + SM_POFF);
    int*    cur   = (int*)(W + SM_CUR);

    // weight prep
    {
        dim3 g44(4, 4, 6);
        k_tcast<<<g44, 256, 0, stream>>>(qw, wqkvT, 256, 256, (size_t)768*256, 0);
        k_tcast<<<g44, 256, 0, stream>>>(kw, wqkvT, 256, 256, (size_t)768*256, 256);
        k_tcast<<<g44, 256, 0, stream>>>(vw, wqkvT, 256, 256, (size_t)768*256, 512);
        k_tcast<<<g44, 256, 0, stream>>>(ow, owT,   256, 256, (size_t)256*256, 0);
        dim3 g1(16, 4, 24);
        k_tcast<<<g1, 256, 0, stream>>>(e_w1, w1T, 256, 1024, (size_t)1024*256, 0);
        dim3 g2(4, 16, 24);
        k_tcast<<<g2, 256, 0, stream>>>(e_w2, w2T, 1024, 256, (size_t)1024*256, 0);
    }

    k_embed<<<T_, D_, 0, stream>>>(x, emb_w, emb_b, h, hb);

    dim3 gqkv(T_/128, 6);
    dim3 gproj(T_/128, 2);
    for (int i = 0; i < NL_; ++i) {
        k_mm_c<<<gqkv, 256, 0, stream>>>(hb, wqkvT + (size_t)i*768*256, qkvb, 768);
        k_attn_mfma<<<B_*H_, 256, 0, stream>>>(qkvb, wfreq + i*H_, wphase + i*H_, aob);
        k_mm_oproj<<<gproj, 256, 0, stream>>>(aob, owT + (size_t)i*D_*D_, h, hb);

        if (i % 2 == 0 && i/2 < NMOE_) {
            int j = i / 2;
            k_zero8<<<1, 64, 0, stream>>>(cnt, cur);
            k_router<<<T_/4, 256, 0, stream>>>(h, router_w + (size_t)j*D_*E_,
                                               router_b + (size_t)j*E_, t2i, t2w);
            k_hist<<<64, 256, 0, stream>>>(t2i, cnt);
            k_prefix<<<1, 1, 0, stream>>>(cnt, poff);
            k_scatter<<<T_/256, 256, 0, stream>>>(t2i, poff, cur, ptok, slot);
            k_moe_ffn<<<CAP_/64, 512, 0, stream>>>(hb,
                                                   w1T + (size_t)j*E_*FF_*D_,
                                                   e_b1 + (size_t)j*E_*FF_,
                                                   w2T + (size_t)j*E_*D_*FF_,
                                                   e_b2 + (size_t)j*E_*D_,
                                                   poff, ptok, yout);
            k_combine<<<T_*64/256, 256, 0, stream>>>(yout, slot, t2w, h, hb);
        }
    }

    k_head<<<B_, 256, 0, stream>>>(h, ln_g, ln_b, pred_w, pred_b, unc_w, unc_b, out);
}